// Round 25
// baseline (249.460 us; speedup 1.0000x reference)
//
#include <hip/hip_runtime.h>
#include <cmath>

namespace {

constexpr int NN0 = 65536;   // nodes stage 0
constexpr int NB  = 32;      // graphs
constexpr int NE  = 524288;  // edges
constexpr int EPG = 16384;   // edges per graph (contiguous)
constexpr int FIN = 129;
constexpr int KP  = 160;     // padded K for lin0 (5 k-tiles of 32)

typedef short bf16x8 __attribute__((ext_vector_type(8)));
typedef float f32x4 __attribute__((ext_vector_type(4)));

__device__ inline float leakyrelu(float z) { return z > 0.f ? z : 0.2f * z; }
__device__ inline float eluf(float z) { return z > 0.f ? z : __expf(z) - 1.f; }
__device__ inline float ftanh(float z) {
  float t = __expf(2.f * z);
  return (t - 1.f) / (t + 1.f);
}

__device__ inline unsigned short f2bf(float x) {
  union { float f; unsigned int u; } v; v.f = x;
  unsigned int r = v.u + 0x7fffu + ((v.u >> 16) & 1u);
  return (unsigned short)(r >> 16);
}
__device__ inline float bf2f(unsigned short h) {
  union { unsigned int u; float f; } v; v.u = ((unsigned int)h) << 16;
  return v.f;
}

__device__ inline float4 f4fma(float4 a, float c, float4 acc) {
  acc.x += a.x * c; acc.y += a.y * c; acc.z += a.z * c; acc.w += a.w * c;
  return acc;
}

// XCD-aware block swizzle (bijective; NB%8==0)
__device__ inline int swz_block(int bid, int bpgl) {
  int x = bid & 7;
  int local = bid >> 3;
  int g = x + ((local >> bpgl) << 3);
  return (g << bpgl) + (local & ((1 << bpgl) - 1));
}

__device__ __forceinline__ void gload_lds16(const unsigned short* g, unsigned short* l) {
  __builtin_amdgcn_global_load_lds((const unsigned int*)g, (unsigned int*)l, 16, 0, 0);
}

// ------- merged prep (1024-thr): scatter0 slices FIRST, then pack_x(8-wide)
//         + 3x pack_w + newid + norms --------------------------------------
__device__ inline void pack_w_body(const float* __restrict__ W, int Kreal, int idx,
                                   unsigned short* __restrict__ hi,
                                   unsigned short* __restrict__ lo) {
  int j = idx & 7;
  int lane = (idx >> 3) & 63;
  int ct = (idx >> 9) & 15;
  int kt = idx >> 13;
  int k = kt * 32 + ((lane >> 4) << 3) + j;
  int c = ct * 16 + (lane & 15);
  float v = (k < Kreal) ? W[(size_t)k * 256 + c] : 0.f;
  unsigned short h = f2bf(v);
  hi[idx] = h;
  lo[idx] = f2bf(v - bf2f(h));
}

constexpr int SLC = 8;  // scatter slices per graph

__global__ __launch_bounds__(1024) void prep(
    const float* __restrict__ x,
    const float* __restrict__ w0, const float* __restrict__ w1,
    const float* __restrict__ w2,
    const float* __restrict__ pw0, const float* __restrict__ pw1,
    const int* __restrict__ src, const int* __restrict__ dst,
    unsigned short* __restrict__ xhi, unsigned short* __restrict__ xlo,
    unsigned short* __restrict__ whi0, unsigned short* __restrict__ wlo0,
    unsigned short* __restrict__ whi1, unsigned short* __restrict__ wlo1,
    unsigned short* __restrict__ whi2, unsigned short* __restrict__ wlo2,
    float* __restrict__ norms, int* __restrict__ newid,
    int* __restrict__ cursor, int* __restrict__ csr) {
  __shared__ int cnt[2048];
  __shared__ int basev[2048];
  const int NSC = NB * SLC;        // 256 scatter blocks (FIRST: start at t=0)
  const int NX = NN0 * KP / 8192;  // 1280 blocks: pack x, 8 elems/thread
  const int NW0 = 5 * 8192 / 1024; // 40
  const int NW = 8 * 8192 / 1024;  // 64
  const int NC = NN0 / 1024;       // 64: newid init
  int b = blockIdx.x, tid = threadIdx.x;
  if (b < NSC) {
    const int g = b / SLC, sl = b % SLC;
    const int e0 = g * EPG + sl * (EPG / SLC);
    const int ne = EPG / SLC;      // 2048 edges per slice
    cnt[tid] = 0; cnt[tid + 1024] = 0;
    __syncthreads();
    for (int i = tid; i < ne; i += 1024)
      atomicAdd(&cnt[dst[e0 + i] - (g << 11)], 1);
    __syncthreads();
    for (int k = tid; k < 2048; k += 1024) {
      int c = cnt[k];
      basev[k] = c ? atomicAdd(&cursor[(g << 11) + k], c) : 0;
    }
    __syncthreads();
    cnt[tid] = 0; cnt[tid + 1024] = 0;
    __syncthreads();
    for (int i = tid; i < ne; i += 1024) {
      int e = e0 + i;
      int d = dst[e];
      int lb = d - (g << 11);
      int pos = basev[lb] + atomicAdd(&cnt[lb], 1);
      if (pos < 64) csr[(size_t)d * 64 + pos] = src[e];
    }
    return;
  }
  b -= NSC;
  if (b < NX) {
    const int base = (b * 1024 + tid) * 8;
    const int row = base / KP;
    const int c0 = base - row * KP;
    const float* xr = &x[(size_t)row * FIN];
    bf16x8 hv, lv;
#pragma unroll
    for (int i = 0; i < 8; i++) {
      const int c = c0 + i;
      float v = (c < FIN) ? xr[c] : 0.f;
      unsigned short h = f2bf(v);
      hv[i] = (short)h;
      lv[i] = (short)f2bf(v - bf2f(h));
    }
    *reinterpret_cast<bf16x8*>(&xhi[base]) = hv;
    *reinterpret_cast<bf16x8*>(&xlo[base]) = lv;
    return;
  }
  b -= NX;
  if (b < NW0) { pack_w_body(w0, FIN, b * 1024 + tid, whi0, wlo0); return; }
  b -= NW0;
  if (b < NW) { pack_w_body(w1, 256, b * 1024 + tid, whi1, wlo1); return; }
  b -= NW;
  if (b < NW) { pack_w_body(w2, 256, b * 1024 + tid, whi2, wlo2); return; }
  b -= NW;
  if (b < NC) {
    newid[b * 1024 + tid] = -1;
    return;
  }
  if (tid < 64) {
    float a0 = 0.f, a1 = 0.f;
#pragma unroll
    for (int j = tid; j < 256; j += 64) {
      float v0 = pw0[j]; a0 += v0 * v0;
      float v1 = pw1[j]; a1 += v1 * v1;
    }
#pragma unroll
    for (int off = 32; off >= 1; off >>= 1) {
      a0 += __shfl_xor(a0, off);
      a1 += __shfl_xor(a1, off);
    }
    if (tid == 0) {
      norms[0] = 1.f / (sqrtf(a0) + 1e-16f);
      norms[1] = 1.f / (sqrtf(a1) + 1e-16f);
    }
  }
}

// -------- FUSED lin0+GAT0 GEMM, BM=32 x BN=256, 40 KB LDS (4 blocks/CU) -----
__global__ __launch_bounds__(256, 4) void gemm_fused(
    const unsigned short* __restrict__ Xhi, const unsigned short* __restrict__ Xlo,
    const unsigned short* __restrict__ B0hi, const unsigned short* __restrict__ B0lo,
    const float* __restrict__ bias0,
    const unsigned short* __restrict__ B1hi, const unsigned short* __restrict__ B1lo,
    float* __restrict__ Out,
    const float* __restrict__ attsrc, const float* __restrict__ attdst,
    float* __restrict__ a_s, float* __restrict__ a_d) {
  __shared__ __align__(16) unsigned short As[2][2][32][32];  // 8 KB
  __shared__ __align__(16) char Hsh[2][32 * 512];            // 32 KB
  const int tid = threadIdx.x;
  const int lane = tid & 63;
  const int w = tid >> 6;
  const int row0 = blockIdx.x * 32;
  const int l15 = lane & 15, q = lane >> 4;
  const int srow16 = lane >> 2;
  const int skc = (lane & 3) * 8;

  // wave w stages: half = w>>1 (0=hi plane, 1=lo plane), rows (w&1)*16 .. +15
  auto stage = [&](int nb, int kt) {
    const int half = w >> 1;
    const int r0 = (w & 1) * 16;
    const size_t goff = (size_t)(row0 + r0 + srow16) * KP + kt * 32 + skc;
    gload_lds16((half ? Xlo : Xhi) + goff, &As[nb][half][r0][0]);
  };

  f32x4 acc[2][4];
#pragma unroll
  for (int mf = 0; mf < 2; mf++)
#pragma unroll
    for (int nf = 0; nf < 4; nf++) acc[mf][nf] = (f32x4)(0.f);

  stage(0, 0);
  __syncthreads();

  // ---- stage 1: x @ W0 (5 k-tiles) ----
#pragma unroll
  for (int kt = 0; kt < 5; ++kt) {
    const int nb = kt & 1;
    if (kt + 1 < 5) stage(nb ^ 1, kt + 1);
    bf16x8 bh[4], bl[4];
#pragma unroll
    for (int nf = 0; nf < 4; nf++) {
      const int ct = w * 4 + nf;
      const size_t bbase = ((size_t)((kt * 16 + ct) * 64 + lane)) << 3;
      bh[nf] = *reinterpret_cast<const bf16x8*>(B0hi + bbase);
      bl[nf] = *reinterpret_cast<const bf16x8*>(B0lo + bbase);
    }
#pragma unroll
    for (int mf = 0; mf < 2; mf++) {
      const int ar = mf * 16 + l15;
      bf16x8 ah = *reinterpret_cast<const bf16x8*>(&As[nb][0][ar][q * 8]);
      bf16x8 al = *reinterpret_cast<const bf16x8*>(&As[nb][1][ar][q * 8]);
#pragma unroll
      for (int nf = 0; nf < 4; nf++) {
        acc[mf][nf] = __builtin_amdgcn_mfma_f32_16x16x32_bf16(ah, bh[nf], acc[mf][nf], 0, 0, 0);
        acc[mf][nf] = __builtin_amdgcn_mfma_f32_16x16x32_bf16(ah, bl[nf], acc[mf][nf], 0, 0, 0);
        acc[mf][nf] = __builtin_amdgcn_mfma_f32_16x16x32_bf16(al, bh[nf], acc[mf][nf], 0, 0, 0);
      }
    }
    __syncthreads();
  }

  // ---- epilogue 1: bias + ReLU -> Hsh (bf16 hi/lo, swizzled) ----
#pragma unroll
  for (int mf = 0; mf < 2; mf++) {
#pragma unroll
    for (int r = 0; r < 4; r++) {
      const int row = mf * 16 + q * 4 + r;
#pragma unroll
      for (int nf = 0; nf < 4; nf++) {
        const int col = w * 64 + nf * 16 + l15;
        float v = acc[mf][nf][r] + bias0[col];
        v = fmaxf(v, 0.f);
        unsigned short h = f2bf(v);
        unsigned short l = f2bf(v - bf2f(h));
        unsigned int off = (unsigned int)(row * 512 + col * 2) ^ ((row & 7) << 4);
        *reinterpret_cast<unsigned short*>(&Hsh[0][off]) = h;
        *reinterpret_cast<unsigned short*>(&Hsh[1][off]) = l;
        acc[mf][nf][r] = 0.f;
      }
    }
  }
  __syncthreads();

  // ---- stage 2: h @ W1 (8 k-tiles from LDS) ----
#pragma unroll
  for (int kt = 0; kt < 8; ++kt) {
    bf16x8 bh[4], bl[4];
#pragma unroll
    for (int nf = 0; nf < 4; nf++) {
      const int ct = w * 4 + nf;
      const size_t bbase = ((size_t)((kt * 16 + ct) * 64 + lane)) << 3;
      bh[nf] = *reinterpret_cast<const bf16x8*>(B1hi + bbase);
      bl[nf] = *reinterpret_cast<const bf16x8*>(B1lo + bbase);
    }
#pragma unroll
    for (int mf = 0; mf < 2; mf++) {
      const int ar = mf * 16 + l15;
      unsigned int off = (unsigned int)(ar * 512 + kt * 64 + q * 16) ^ ((ar & 7) << 4);
      bf16x8 ah = *reinterpret_cast<const bf16x8*>(&Hsh[0][off]);
      bf16x8 al = *reinterpret_cast<const bf16x8*>(&Hsh[1][off]);
#pragma unroll
      for (int nf = 0; nf < 4; nf++) {
        acc[mf][nf] = __builtin_amdgcn_mfma_f32_16x16x32_bf16(ah, bh[nf], acc[mf][nf], 0, 0, 0);
        acc[mf][nf] = __builtin_amdgcn_mfma_f32_16x16x32_bf16(ah, bl[nf], acc[mf][nf], 0, 0, 0);
        acc[mf][nf] = __builtin_amdgcn_mfma_f32_16x16x32_bf16(al, bh[nf], acc[mf][nf], 0, 0, 0);
      }
    }
  }

  // ---- epilogue 2: hW0 out + a_s/a_d ----
#pragma unroll
  for (int mf = 0; mf < 2; mf++) {
    const int rowb = row0 + mf * 16 + q * 4;
#pragma unroll
    for (int r = 0; r < 4; r++) {
#pragma unroll
      for (int nf = 0; nf < 4; nf++) {
        const int col = w * 64 + nf * 16 + l15;
        Out[(size_t)(rowb + r) * 256 + col] = acc[mf][nf][r];
      }
    }
  }
  const int head = w;
  float sv[4], dv[4];
#pragma unroll
  for (int nf = 0; nf < 4; nf++) {
    sv[nf] = attsrc[head * 64 + nf * 16 + l15];
    dv[nf] = attdst[head * 64 + nf * 16 + l15];
  }
#pragma unroll
  for (int mf = 0; mf < 2; mf++) {
#pragma unroll
    for (int r = 0; r < 4; r++) {
      float ps = 0.f, pd = 0.f;
#pragma unroll
      for (int nf = 0; nf < 4; nf++) {
        ps += acc[mf][nf][r] * sv[nf];
        pd += acc[mf][nf][r] * dv[nf];
      }
#pragma unroll
      for (int off = 8; off >= 1; off >>= 1) {
        ps += __shfl_xor(ps, off);
        pd += __shfl_xor(pd, off);
      }
      if (l15 == 0) {
        const int row = row0 + mf * 16 + q * 4 + r;
        a_s[(size_t)row * 4 + head] = ps;
        a_d[(size_t)row * 4 + head] = pd;
      }
    }
  }
}

// ------ split-bf16 GEMM (GAT1) + fused attpool_reduce(pool0) tail blocks ----
template <int KT, bool INDIR>
__global__ __launch_bounds__(256, 2) void gemm_mfma(
    const unsigned short* __restrict__ Xhi, const unsigned short* __restrict__ Xlo,
    int ldx,
    const unsigned short* __restrict__ Bhi, const unsigned short* __restrict__ Blo,
    float* __restrict__ Out,
    const float* __restrict__ attsrc, const float* __restrict__ attdst,
    float* __restrict__ a_s, float* __restrict__ a_d,
    const int* __restrict__ rowmap, const float* __restrict__ tscale, int swzl,
    int ngemm, const float* __restrict__ partials, float* __restrict__ outp,
    int nch) {
  __shared__ __align__(16) unsigned short As[2][2][128][32];  // 32 KB
  const int tid = threadIdx.x;
  if ((int)blockIdx.x >= ngemm) {
    int g = blockIdx.x - ngemm, c = tid;
    float a = 0.f;
    for (int s = 0; s < nch; s++) a += partials[((size_t)g * nch + s) * 256 + c];
    outp[g * 256 + c] = a;
    return;
  }
  const int lane = tid & 63;
  const int w = tid >> 6;
  const int rb = (swzl >= 0) ? swz_block(blockIdx.x, swzl) : blockIdx.x;
  const int row0 = rb * 128;
  const int l15 = lane & 15, q = lane >> 4;
  const int sl4 = lane >> 2;
  const int skc = (lane & 3) * 8;

  size_t gr[2];
#pragma unroll
  for (int i = 0; i < 2; i++) {
    int lr = row0 + (w + 4 * i) * 16 + sl4;
    gr[i] = INDIR ? (size_t)rowmap[lr] : (size_t)lr;
  }

  auto stage = [&](int nb, int kt) {
#pragma unroll
    for (int i = 0; i < 2; i++) {
      const int rbase = (w + 4 * i) * 16;
      const size_t goff = gr[i] * ldx + kt * 32 + skc;
      gload_lds16(Xhi + goff, &As[nb][0][rbase][0]);
      gload_lds16(Xlo + goff, &As[nb][1][rbase][0]);
    }
  };

  f32x4 acc[8][4];
#pragma unroll
  for (int mf = 0; mf < 8; mf++)
#pragma unroll
    for (int nf = 0; nf < 4; nf++) acc[mf][nf] = (f32x4)(0.f);

  stage(0, 0);
  __syncthreads();

#pragma unroll
  for (int kt = 0; kt < KT; ++kt) {
    const int nb = kt & 1;
    if (kt + 1 < KT) stage(nb ^ 1, kt + 1);
    bf16x8 bh[4], bl[4];
#pragma unroll
    for (int nf = 0; nf < 4; nf++) {
      const int ct = w * 4 + nf;
      const size_t bbase = ((size_t)((kt * 16 + ct) * 64 + lane)) << 3;
      bh[nf] = *reinterpret_cast<const bf16x8*>(Bhi + bbase);
      bl[nf] = *reinterpret_cast<const bf16x8*>(Blo + bbase);
    }
#pragma unroll
    for (int mf = 0; mf < 8; mf++) {
      const int ar = mf * 16 + l15;
      bf16x8 ah = *reinterpret_cast<const bf16x8*>(&As[nb][0][ar][q * 8]);
      bf16x8 al = *reinterpret_cast<const bf16x8*>(&As[nb][1][ar][q * 8]);
#pragma unroll
      for (int nf = 0; nf < 4; nf++) {
        acc[mf][nf] = __builtin_amdgcn_mfma_f32_16x16x32_bf16(ah, bh[nf], acc[mf][nf], 0, 0, 0);
        acc[mf][nf] = __builtin_amdgcn_mfma_f32_16x16x32_bf16(ah, bl[nf], acc[mf][nf], 0, 0, 0);
        acc[mf][nf] = __builtin_amdgcn_mfma_f32_16x16x32_bf16(al, bh[nf], acc[mf][nf], 0, 0, 0);
      }
    }
    __syncthreads();
  }

#pragma unroll
  for (int mf = 0; mf < 8; mf++) {
    const int rowb = row0 + mf * 16 + q * 4;
#pragma unroll
    for (int r = 0; r < 4; r++) {
      const float ts = INDIR ? tscale[rowb + r] : 1.f;
#pragma unroll
      for (int nf = 0; nf < 4; nf++) {
        float v = acc[mf][nf][r];
        if constexpr (INDIR) v *= ts;
        const int col = w * 64 + nf * 16 + l15;
        Out[(size_t)(rowb + r) * 256 + col] = v;
      }
    }
  }
  const int head = w;
  float sv[4], dv[4];
#pragma unroll
  for (int nf = 0; nf < 4; nf++) {
    sv[nf] = attsrc[head * 64 + nf * 16 + l15];
    dv[nf] = attdst[head * 64 + nf * 16 + l15];
  }
#pragma unroll
  for (int mf = 0; mf < 8; mf++) {
#pragma unroll
    for (int r = 0; r < 4; r++) {
      float ps = 0.f, pd = 0.f;
#pragma unroll
      for (int nf = 0; nf < 4; nf++) {
        ps += acc[mf][nf][r] * sv[nf];
        pd += acc[mf][nf][r] * dv[nf];
      }
#pragma unroll
      for (int off = 8; off >= 1; off >>= 1) {
        ps += __shfl_xor(ps, off);
        pd += __shfl_xor(pd, off);
      }
      if (l15 == 0) {
        const int row = row0 + mf * 16 + q * 4 + r;
        float ts = INDIR ? tscale[row] : 1.f;
        a_s[(size_t)row * 4 + head] = ps * ts;
        a_d[(size_t)row * 4 + head] = pd * ts;
      }
    }
  }
}

// --------- per-dest-node GAT: 2 nodes/wave; 16-lane group = node x 2 heads --
__global__ __launch_bounds__(256) void gat_node8(
    const int* __restrict__ cursor, const int* __restrict__ csr,
    const float* __restrict__ a_s, const float* __restrict__ a_d,
    const float* __restrict__ hW, const float* __restrict__ bias,
    const float* __restrict__ pool_w, const float* __restrict__ inv_norm,
    const float* __restrict__ gate_w,
    unsigned short* __restrict__ outHi, unsigned short* __restrict__ outLo,
    float* __restrict__ score, float* __restrict__ graw, int bpgl) {
  const int lane = threadIdx.x & 63;
  const int wv = threadIdx.x >> 6;
  const int dbase = swz_block(blockIdx.x, bpgl) * 8 + wv * 2;
  const int g = lane >> 4, l16 = lane & 15;
  const int d = dbase + (g >> 1);
  const int h0 = (g & 1) * 2;

  const int deg = min(cursor[d], 63);
  const int dim = deg + 1;  // + self loop

  int dmaxw = dim;
  dmaxw = max(dmaxw, __shfl_xor(dmaxw, 32));
  const int nch = (dmaxw + 15) >> 4;

  const float2 ad2 = *reinterpret_cast<const float2*>(&a_d[(size_t)d * 4 + h0]);

  int sreg[4];
  float L0[4], L1[4];
#pragma unroll
  for (int c = 0; c < 4; c++) {
    if (c < nch) {
      const int j = c * 16 + l16;
      const bool has = j < dim;
      int s = (j < deg) ? csr[(size_t)d * 64 + j] : d;
      sreg[c] = s;
      float2 as2 = *reinterpret_cast<const float2*>(&a_s[(size_t)s * 4 + h0]);
      L0[c] = has ? leakyrelu(as2.x + ad2.x) : -1e30f;
      L1[c] = has ? leakyrelu(as2.y + ad2.y) : -1e30f;
    } else {
      sreg[c] = d;
      L0[c] = -1e30f; L1[c] = -1e30f;
    }
  }
  float m0 = fmaxf(fmaxf(L0[0], L0[1]), fmaxf(L0[2], L0[3]));
  float m1 = fmaxf(fmaxf(L1[0], L1[1]), fmaxf(L1[2], L1[3]));
#pragma unroll
  for (int off = 1; off <= 8; off <<= 1) {
    m0 = fmaxf(m0, __shfl_xor(m0, off));
    m1 = fmaxf(m1, __shfl_xor(m1, off));
  }
  float e0[4], e1[4];
  float dn0 = 0.f, dn1 = 0.f;
#pragma unroll
  for (int c = 0; c < 4; c++) {
    if (c < nch) {
      e0[c] = __expf(L0[c] - m0);
      e1[c] = __expf(L1[c] - m1);
      dn0 += e0[c]; dn1 += e1[c];
    } else {
      e0[c] = 0.f; e1[c] = 0.f;
    }
  }
#pragma unroll
  for (int off = 1; off <= 8; off <<= 1) {
    dn0 += __shfl_xor(dn0, off);
    dn1 += __shfl_xor(dn1, off);
  }

  float4 acc0 = {0.f, 0.f, 0.f, 0.f}, acc1 = {0.f, 0.f, 0.f, 0.f};
#pragma unroll
  for (int c = 0; c < 4; c++) {
    if (c < nch) {
      const int tmax = min(16, dmaxw - c * 16);
#pragma unroll 4
      for (int tt = 0; tt < tmax; tt++) {
        const int idx = g * 16 + tt;
        int st = __shfl(sreg[c], idx);
        float c0 = __shfl(e0[c], idx), c1 = __shfl(e1[c], idx);
        if (c * 16 + tt < dim) {
          const float4* hp = reinterpret_cast<const float4*>(&hW[(size_t)st * 256]) + l16;
          acc0 = f4fma(hp[h0 * 16],       c0, acc0);
          acc1 = f4fma(hp[(h0 + 1) * 16], c1, acc1);
        }
      }
    }
  }

  const float iv0 = 1.f / (dn0 + 1e-16f), iv1 = 1.f / (dn1 + 1e-16f);
  float sd = 0.f, gd = 0.f;
#pragma unroll
  for (int h = 0; h < 2; h++) {
    const int coff = (h0 + h) * 64 + l16 * 4;
    float4 vb = h ? acc1 : acc0;
    float iv = h ? iv1 : iv0;
    float4 bb = *reinterpret_cast<const float4*>(&bias[coff]);
    float4 o;
    o.x = eluf(vb.x * iv + bb.x);
    o.y = eluf(vb.y * iv + bb.y);
    o.z = eluf(vb.z * iv + bb.z);
    o.w = eluf(vb.w * iv + bb.w);
    ushort4 oh, ol;
    oh.x = f2bf(o.x); ol.x = f2bf(o.x - bf2f(oh.x));
    oh.y = f2bf(o.y); ol.y = f2bf(o.y - bf2f(oh.y));
    oh.z = f2bf(o.z); ol.z = f2bf(o.z - bf2f(oh.z));
    oh.w = f2bf(o.w); ol.w = f2bf(o.w - bf2f(oh.w));
    *reinterpret_cast<ushort4*>(&outHi[(size_t)d * 256 + coff]) = oh;
    *reinterpret_cast<ushort4*>(&outLo[(size_t)d * 256 + coff]) = ol;
    float4 pw = *reinterpret_cast<const float4*>(&pool_w[coff]);
    float4 gw = *reinterpret_cast<const float4*>(&gate_w[coff]);
    sd += o.x * pw.x + o.y * pw.y + o.z * pw.z + o.w * pw.w;
    gd += o.x * gw.x + o.y * gw.y + o.z * gw.z + o.w * gw.w;
  }
#pragma unroll
  for (int off = 1; off <= 16; off <<= 1) {
    sd += __shfl_xor(sd, off);
    gd += __shfl_xor(gd, off);
  }
  if ((lane & 31) == 0) {
    score[d] = sd * inv_norm[0];
    graw[d] = gd;
  }
}

// ------- adaptive-range histogram top-k select + fused attpool softmax ------
__global__ __launch_bounds__(1024) void topk_hsel(
    const float* __restrict__ score, const float* __restrict__ graw,
    const float* __restrict__ gate_b, int npg, int k,
    int* __restrict__ perm, int* __restrict__ newid,
    float* __restrict__ gate, float* __restrict__ tsc) {
  __shared__ unsigned keys[2048];
  __shared__ int hist[1024];
  __shared__ int ssum[1024];
  __shared__ int segtot[16];
  __shared__ unsigned wmin[16], wmax[16];
  __shared__ int sstate[3];
  __shared__ int scnt;
  __shared__ int candi[512];
  __shared__ unsigned candk[512];
  __shared__ float fred[1024];
  const int g = blockIdx.x, tid = threadIdx.x;
  const int wv = tid >> 6, ln = tid & 63;
  const size_t base = (size_t)g * npg;

  unsigned mymin = 0xFFFFFFFFu, mymax = 0u;
  for (int i = tid; i < npg; i += 1024) {
    unsigned u = __float_as_uint(score[base + i]);
    u = (u & 0x80000000u) ? ~u : (u | 0x80000000u);
    keys[i] = u;
    mymin = min(mymin, u);
    mymax = max(mymax, u);
  }
#pragma unroll
  for (int off = 32; off >= 1; off >>= 1) {
    mymin = min(mymin, (unsigned)__shfl_xor((int)mymin, off));
    mymax = max(mymax, (unsigned)__shfl_xor((int)mymax, off));
  }
  if (ln == 0) { wmin[wv] = mymin; wmax[wv] = mymax; }
  __syncthreads();
  unsigned lo, hi;
  {
    unsigned a = 0xFFFFFFFFu, b = 0u;
#pragma unroll
    for (int i = 0; i < 16; i++) { a = min(a, wmin[i]); b = max(b, wmax[i]); }
    lo = a; hi = b;
  }
  int need = k;

  for (int iter = 0; iter < 4; ++iter) {
    unsigned long long range = (unsigned long long)(hi - lo) + 1ull;
    unsigned width = (unsigned)((range + 1023ull) >> 10);
    hist[tid] = 0;
    __syncthreads();
    for (int i = tid; i < npg; i += 1024) {
      unsigned u = keys[i];
      if (u >= lo && u <= hi) atomicAdd(&hist[(u - lo) / width], 1);
    }
    __syncthreads();
    int v = hist[tid];
    int s = v;
#pragma unroll
    for (int off = 1; off < 64; off <<= 1) {
      int t = __shfl_down(s, off);
      if (ln + off < 64) s += t;
    }
    if (ln == 0) segtot[wv] = s;
    __syncthreads();
    if (tid == 0) {
      int acc = 0;
      for (int i = 15; i >= 0; i--) { int t = segtot[i]; segtot[i] = acc; acc += t; }
    }
    __syncthreads();
    int S = s + segtot[wv];
    ssum[tid] = S;
    __syncthreads();
    int gt = (tid == 1023) ? 0 : ssum[tid + 1];
    if (S >= need && gt < need) {
      sstate[0] = tid;
      sstate[1] = gt;
      sstate[2] = hist[tid];
    }
    __syncthreads();
    const int bstar = sstate[0], cntAbove = sstate[1], m = sstate[2];
    unsigned nlo = lo + (unsigned)bstar * width;
    unsigned long long nhiu = (unsigned long long)lo + (unsigned long long)(bstar + 1) * width - 1ull;
    unsigned nhi = (nhiu > (unsigned long long)hi) ? hi : (unsigned)nhiu;
    need -= cntAbove;
    lo = nlo; hi = nhi;
    __syncthreads();
    if (width == 1 || m <= 256) break;
  }

  if (tid == 0) scnt = 0;
  __syncthreads();
  for (int i = tid; i < npg; i += 1024) {
    unsigned u = keys[i];
    if (u >= lo && u <= hi) {
      int pidx = atomicAdd(&scnt, 1);
      if (pidx < 512) { candi[pidx] = i; candk[pidx] = u; }
    }
  }
  __syncthreads();
  const int m_all = scnt;
  const float gb = gate_b[0];
  if (tid == 0) scnt = 0;
  __syncthreads();
  for (int i = tid; i < npg; i += 1024) {
    if (keys[i] > hi) {
      int pos = atomicAdd(&scnt, 1);
      int node = (int)(base + i);
      perm[g * k + pos] = node;
      if (newid) newid[node] = g * k + pos;
      float ts = ftanh(score[base + i]);
      tsc[g * k + pos] = ts;
      gate[g * k + pos] = ts * graw[node] + gb;
    }
  }
  __syncthreads();
  const int nAbove = scnt;
  if (m_all <= 512) {
    for (int c = tid; c < m_all; c += 1024) {
      unsigned u = candk[c];
      int i = candi[c];
      int rank = 0;
      for (int j = 0; j < m_all; j++) {
        unsigned vk = candk[j];
        rank += (vk > u) || (vk == u && candi[j] < i);
      }
      if (rank < need) {
        int pos = nAbove + rank;
        int node = (int)(base + i);
        perm[g * k + pos] = node;
        if (newid) newid[node] = g * k + pos;
        float ts = ftanh(score[base + i]);
        tsc[g * k + pos] = ts;
        gate[g * k + pos] = ts * graw[node] + gb;
      }
    }
  } else {
    for (int i = tid; i < npg; i += 1024) {
      unsigned u = keys[i];
      if (u >= lo && u <= hi) {
        int rank = 0;
        for (int j = 0; j < npg; j++) {
          unsigned vk = keys[j];
          if (vk >= lo && vk <= hi) rank += (vk > u) || (vk == u && j < i);
        }
        if (rank < need) {
          int pos = nAbove + rank;
          int node = (int)(base + i);
          perm[g * k + pos] = node;
          if (newid) newid[node] = g * k + pos;
          float ts = ftanh(score[base + i]);
          tsc[g * k + pos] = ts;
          gate[g * k + pos] = ts * graw[node] + gb;
        }
      }
    }
  }
  __syncthreads();

  // ---- fused attpool softmax: gate[j] <- exp(gate-m)/sum * tsc[j] ----
  float gv = (tid < k) ? gate[g * k + tid] : -1e30f;
  fred[tid] = gv;
  __syncthreads();
  for (int s = 512; s >= 1; s >>= 1) {
    if (tid < s) fred[tid] = fmaxf(fred[tid], fred[tid + s]);
    __syncthreads();
  }
  const float gm = fred[0];
  __syncthreads();
  float ge = (tid < k) ? __expf(gv - gm) : 0.f;
  fred[tid] = ge;
  __syncthreads();
  for (int s = 512; s >= 1; s >>= 1) {
    if (tid < s) fred[tid] += fred[tid + s];
    __syncthreads();
  }
  const float ginv = 1.f / fred[0];
  if (tid < k) gate[g * k + tid] = ge * ginv * tsc[g * k + tid];
}

// ---- pool tail (1024-thr): scatter1 slices FIRST (two-pass, 8 blocks/graph),
//      then attpool weighted gather-sum blocks (4 chunks/block) --------------
__global__ __launch_bounds__(1024) void pool_tail(
    const unsigned short* __restrict__ xhi, const unsigned short* __restrict__ xlo,
    const int* __restrict__ perm, const float* __restrict__ wfin,
    float* __restrict__ partials, int npg, int bpgl, int nsc,
    const int* __restrict__ src, const int* __restrict__ dst,
    const int* __restrict__ newid, int* __restrict__ cursor2,
    int* __restrict__ csr) {
  __shared__ int cnt[1024];
  __shared__ int basev[1024];
  const int tid = threadIdx.x;
  if ((int)blockIdx.x < nsc) {
    const int g = blockIdx.x / SLC, sl = blockIdx.x % SLC;
    const int e0 = g * EPG + sl * (EPG / SLC);
    const int ne = EPG / SLC;
    cnt[tid] = 0;
    __syncthreads();
    for (int i = tid; i < ne; i += 1024) {
      int e = e0 + i;
      int s = newid[src[e]], d = newid[dst[e]];
      if (s >= 0 && d >= 0) atomicAdd(&cnt[d - (g << 10)], 1);
    }
    __syncthreads();
    {
      int c = cnt[tid];
      basev[tid] = c ? atomicAdd(&cursor2[(g << 10) + tid], c) : 0;
    }
    __syncthreads();
    cnt[tid] = 0;
    __syncthreads();
    for (int i = tid; i < ne; i += 1024) {
      int e = e0 + i;
      int s = newid[src[e]], d = newid[dst[e]];
      if (s < 0 || d < 0) continue;
      int lb = d - (g << 10);
      int pos = basev[lb] + atomicAdd(&cnt[lb], 1);
      if (pos < 64) csr[(size_t)d * 64 + pos] = s;
    }
    return;
  }
  // attpool sum blocks
  int rel = blockIdx.x - nsc;
  int o = swz_block(rel, bpgl);
  int g = o >> bpgl, lb = o & ((1 << bpgl) - 1);
  int part = tid >> 8, c = tid & 255;
  int sub = lb * 4 + part;
  size_t r0 = (size_t)g * npg + sub * 32;
  float a = 0.f;
#pragma unroll 8
  for (int i = 0; i < 32; i++) {
    float wv = wfin[r0 + i];
    size_t node = (size_t)perm[r0 + i];
    float v = bf2f(xhi[node * 256 + c]) + bf2f(xlo[node * 256 + c]);
    a += wv * v;
  }
  partials[((size_t)g * (npg >> 5) + sub) * 256 + c] = a;
}

__global__ __launch_bounds__(256) void attpool_reduce(const float* __restrict__ partials,
                                                      float* __restrict__ out,
                                                      int nch, int acc_flag) {
  int g = blockIdx.x, c = threadIdx.x;
  float a = 0.f;
  for (int s = 0; s < nch; s++) a += partials[((size_t)g * nch + s) * 256 + c];
  if (acc_flag) out[g * 256 + c] += a;
  else out[g * 256 + c] = a;
}

}  // namespace

extern "C" void kernel_launch(void* const* d_in, const int* in_sizes, int n_in,
                              void* d_out, int out_size, void* d_ws, size_t ws_size,
                              hipStream_t stream) {
  (void)in_sizes; (void)n_in; (void)out_size; (void)ws_size;
  const float* x       = (const float*)d_in[0];
  const int*   ei      = (const int*)d_in[1];
  const float* lin0_w  = (const float*)d_in[2];
  const float* lin0_b  = (const float*)d_in[3];
  const float* gat0_W  = (const float*)d_in[4];
  const float* gat0_as = (const float*)d_in[5];
  const float* gat0_ad = (const float*)d_in[6];
  const float* gat0_b  = (const float*)d_in[7];
  const float* pool0_w = (const float*)d_in[8];
  const float* gat1_W  = (const float*)d_in[9];
  const float* gat1_as = (const float*)d_in[10];
  const float* gat1_ad = (const float*)d_in[11];
  const float* gat1_b  = (const float*)d_in[12];
  const float* pool1_w = (const float*)d_in[13];
  const float* gate_w  = (const float*)d_in[14];
  const float* gate_b  = (const float*)d_in[15];
  float* out = (float*)d_out;
  const int* srcp = ei;
  const int* dstp = ei + NE;

  char* wsb = (char*)d_ws;
  size_t cur = 0;
  auto alloc = [&](size_t bytes) {
    void* p = wsb + cur;
    cur = (cur + bytes + 255) & ~(size_t)255;
    return p;
  };
  char* regA = (char*)alloc((size_t)NN0 * 256 * 4);        // out0hi/lo
  char* regB = (char*)alloc((size_t)NN0 * 256 * 4);        // hW0 -> {hW1, out1hi/lo}
  char* regD = (char*)alloc((size_t)NN0 * KP * 2 * 2);     // xhi/xlo
  float* a_s     = (float*)alloc((size_t)NN0 * 4 * 4);
  float* a_d     = (float*)alloc((size_t)NN0 * 4 * 4);
  int*   cursor  = (int*)alloc((size_t)NN0 * 4);
  int*   cursor2 = (int*)alloc((size_t)32768 * 4);
  int*   csr     = (int*)alloc((size_t)NN0 * 64 * 4);
  float* score   = (float*)alloc((size_t)NN0 * 4);
  float* graw    = (float*)alloc((size_t)NN0 * 4);
  int*   newid   = (int*)alloc((size_t)NN0 * 4);
  int*   perm0   = (int*)alloc((size_t)32768 * 4);
  int*   perm1   = (int*)alloc((size_t)16384 * 4);
  float* tsc0    = (float*)alloc((size_t)32768 * 4);
  float* tsc1    = (float*)alloc((size_t)16384 * 4);
  float* gate0   = (float*)alloc((size_t)32768 * 4);
  float* gate1   = (float*)alloc((size_t)16384 * 4);
  float* partials= (float*)alloc((size_t)NB * 32 * 256 * 4);
  float* norms   = (float*)alloc(2 * 4);
  unsigned short* whi0 = (unsigned short*)alloc((size_t)5 * 8192 * 2);
  unsigned short* wlo0 = (unsigned short*)alloc((size_t)5 * 8192 * 2);
  unsigned short* whi1 = (unsigned short*)alloc((size_t)8 * 8192 * 2);
  unsigned short* wlo1 = (unsigned short*)alloc((size_t)8 * 8192 * 2);
  unsigned short* whi2 = (unsigned short*)alloc((size_t)8 * 8192 * 2);
  unsigned short* wlo2 = (unsigned short*)alloc((size_t)8 * 8192 * 2);

  unsigned short* xhi = (unsigned short*)regD;
  unsigned short* xlo = xhi + (size_t)NN0 * KP;
  float* hW0  = (float*)regB;
  unsigned short* out0hi = (unsigned short*)regA;
  unsigned short* out0lo = out0hi + (size_t)NN0 * 256;
  float* hW1  = (float*)regB;                              // overwrites hW0
  unsigned short* out1hi = (unsigned short*)(regB + (size_t)32768 * 256 * 4);
  unsigned short* out1lo = out1hi + (size_t)32768 * 256;

  // ---- zero cursors for the two-pass scatters (async, capture-safe) ----
  hipMemsetAsync(cursor, 0, (size_t)NN0 * 4, stream);
  hipMemsetAsync(cursor2, 0, (size_t)32768 * 4, stream);

  // ---- merged prep (scatter0 slices first, then packs) ----
  {
    int grid = NB * SLC + NN0 * KP / 8192 + 40 + 64 + 64 + 64 + 1;
    prep<<<grid, 1024, 0, stream>>>(x, lin0_w, gat0_W, gat1_W, pool0_w, pool1_w,
                                    srcp, dstp,
                                    xhi, xlo, whi0, wlo0, whi1, wlo1, whi2, wlo2,
                                    norms, newid, cursor, csr);
  }

  // ---- fused lin0+GAT0 GEMM -> hW0 + a_s/a_d (BM=32, 4 blocks/CU) ----
  gemm_fused<<<NN0 / 32, 256, 0, stream>>>(
      xhi, xlo, whi0, wlo0, lin0_b, whi1, wlo1, hW0,
      gat0_as, gat0_ad, a_s, a_d);

  gat_node8<<<NN0 / 8, 256, 0, stream>>>(cursor, csr, a_s, a_d, hW0,
                                         gat0_b, pool0_w, norms, gate_w,
                                         out0hi, out0lo, score, graw, 8);

  // ---- pool0: top-1024 of 2048 per graph (weights finalized in-kernel) ----
  topk_hsel<<<NB, 1024, 0, stream>>>(score, graw, gate_b, 2048, 1024,
                                     perm0, newid, gate0, tsc0);
  pool_tail<<<NB * SLC + NB * 8, 1024, 0, stream>>>(
      out0hi, out0lo, perm0, gate0, partials, 1024, 3, NB * SLC,
      srcp, dstp, newid, cursor2, csr);

  // ---- GAT1 GEMM (+ fused attpool_reduce(pool0) tail blocks) ----
  gemm_mfma<8, true><<<32768 / 128 + NB, 256, 0, stream>>>(
      out0hi, out0lo, 256, whi2, wlo2, hW1,
      gat1_as, gat1_ad, a_s, a_d, perm0, tsc0, 3,
      32768 / 128, partials, out, 32);

  gat_node8<<<32768 / 8, 256, 0, stream>>>(cursor2, csr, a_s, a_d, hW1,
                                           gat1_b, pool1_w, norms + 1, gate_w,
                                           out1hi, out1lo, score, graw, 7);

  // ---- pool1: top-512 of 1024 per graph ----
  topk_hsel<<<NB, 1024, 0, stream>>>(score, graw, gate_b, 1024, 512,
                                     perm1, nullptr, gate1, tsc1);
  pool_tail<<<NB * 4, 1024, 0, stream>>>(
      out1hi, out1lo, perm1, gate1, partials, 512, 2, 0,
      nullptr, nullptr, nullptr, nullptr, nullptr);
  attpool_reduce<<<NB, 256, 0, stream>>>(partials, out, 16, 1);
}

// Round 26
// 248.999 us; speedup vs baseline: 1.0019x; 1.0019x over previous
//
#include <hip/hip_runtime.h>
#include <cmath>

namespace {

constexpr int NN0 = 65536;   // nodes stage 0
constexpr int NB  = 32;      // graphs
constexpr int NE  = 524288;  // edges
constexpr int EPG = 16384;   // edges per graph (contiguous)
constexpr int FIN = 129;
constexpr int KP  = 160;     // padded K for lin0 (5 k-tiles of 32)

typedef short bf16x8 __attribute__((ext_vector_type(8)));
typedef float f32x4 __attribute__((ext_vector_type(4)));

__device__ inline float leakyrelu(float z) { return z > 0.f ? z : 0.2f * z; }
__device__ inline float eluf(float z) { return z > 0.f ? z : __expf(z) - 1.f; }
__device__ inline float ftanh(float z) {
  float t = __expf(2.f * z);
  return (t - 1.f) / (t + 1.f);
}

__device__ inline unsigned short f2bf(float x) {
  union { float f; unsigned int u; } v; v.f = x;
  unsigned int r = v.u + 0x7fffu + ((v.u >> 16) & 1u);
  return (unsigned short)(r >> 16);
}
__device__ inline float bf2f(unsigned short h) {
  union { unsigned int u; float f; } v; v.u = ((unsigned int)h) << 16;
  return v.f;
}

__device__ inline float4 f4fma(float4 a, float c, float4 acc) {
  acc.x += a.x * c; acc.y += a.y * c; acc.z += a.z * c; acc.w += a.w * c;
  return acc;
}

// XCD-aware block swizzle (bijective; NB%8==0)
__device__ inline int swz_block(int bid, int bpgl) {
  int x = bid & 7;
  int local = bid >> 3;
  int g = x + ((local >> bpgl) << 3);
  return (g << bpgl) + (local & ((1 << bpgl) - 1));
}

__device__ __forceinline__ void gload_lds16(const unsigned short* g, unsigned short* l) {
  __builtin_amdgcn_global_load_lds((const unsigned int*)g, (unsigned int*)l, 16, 0, 0);
}

// ------- merged prep (1024-thr): scatter0 slices FIRST, then pack_x(8-wide)
//         + 3x pack_w + newid + norms --------------------------------------
__device__ inline void pack_w_body(const float* __restrict__ W, int Kreal, int idx,
                                   unsigned short* __restrict__ hi,
                                   unsigned short* __restrict__ lo) {
  int j = idx & 7;
  int lane = (idx >> 3) & 63;
  int ct = (idx >> 9) & 15;
  int kt = idx >> 13;
  int k = kt * 32 + ((lane >> 4) << 3) + j;
  int c = ct * 16 + (lane & 15);
  float v = (k < Kreal) ? W[(size_t)k * 256 + c] : 0.f;
  unsigned short h = f2bf(v);
  hi[idx] = h;
  lo[idx] = f2bf(v - bf2f(h));
}

constexpr int SLC = 8;  // scatter slices per graph

__global__ __launch_bounds__(1024) void prep(
    const float* __restrict__ x,
    const float* __restrict__ w0, const float* __restrict__ w1,
    const float* __restrict__ w2,
    const float* __restrict__ pw0, const float* __restrict__ pw1,
    const int* __restrict__ src, const int* __restrict__ dst,
    unsigned short* __restrict__ xhi, unsigned short* __restrict__ xlo,
    unsigned short* __restrict__ whi0, unsigned short* __restrict__ wlo0,
    unsigned short* __restrict__ whi1, unsigned short* __restrict__ wlo1,
    unsigned short* __restrict__ whi2, unsigned short* __restrict__ wlo2,
    float* __restrict__ norms, int* __restrict__ newid,
    int* __restrict__ cursor, int* __restrict__ csr) {
  __shared__ int cnt[2048];
  __shared__ int basev[2048];
  const int NSC = NB * SLC;        // 256 scatter blocks (FIRST: start at t=0)
  const int NX = NN0 * KP / 8192;  // 1280 blocks: pack x, 8 elems/thread
  const int NW0 = 5 * 8192 / 1024; // 40
  const int NW = 8 * 8192 / 1024;  // 64
  const int NC = NN0 / 1024;       // 64: newid init
  int b = blockIdx.x, tid = threadIdx.x;
  if (b < NSC) {
    const int g = b / SLC, sl = b % SLC;
    const int e0 = g * EPG + sl * (EPG / SLC);
    const int ne = EPG / SLC;      // 2048 edges per slice
    cnt[tid] = 0; cnt[tid + 1024] = 0;
    __syncthreads();
    for (int i = tid; i < ne; i += 1024)
      atomicAdd(&cnt[dst[e0 + i] - (g << 11)], 1);
    __syncthreads();
    for (int k = tid; k < 2048; k += 1024) {
      int c = cnt[k];
      basev[k] = c ? atomicAdd(&cursor[(g << 11) + k], c) : 0;
    }
    __syncthreads();
    cnt[tid] = 0; cnt[tid + 1024] = 0;
    __syncthreads();
    for (int i = tid; i < ne; i += 1024) {
      int e = e0 + i;
      int d = dst[e];
      int lb = d - (g << 11);
      int pos = basev[lb] + atomicAdd(&cnt[lb], 1);
      if (pos < 64) csr[(size_t)d * 64 + pos] = src[e];
    }
    return;
  }
  b -= NSC;
  if (b < NX) {
    const int base = (b * 1024 + tid) * 8;
    const int row = base / KP;
    const int c0 = base - row * KP;
    const float* xr = &x[(size_t)row * FIN];
    bf16x8 hv, lv;
#pragma unroll
    for (int i = 0; i < 8; i++) {
      const int c = c0 + i;
      float v = (c < FIN) ? xr[c] : 0.f;
      unsigned short h = f2bf(v);
      hv[i] = (short)h;
      lv[i] = (short)f2bf(v - bf2f(h));
    }
    *reinterpret_cast<bf16x8*>(&xhi[base]) = hv;
    *reinterpret_cast<bf16x8*>(&xlo[base]) = lv;
    return;
  }
  b -= NX;
  if (b < NW0) { pack_w_body(w0, FIN, b * 1024 + tid, whi0, wlo0); return; }
  b -= NW0;
  if (b < NW) { pack_w_body(w1, 256, b * 1024 + tid, whi1, wlo1); return; }
  b -= NW;
  if (b < NW) { pack_w_body(w2, 256, b * 1024 + tid, whi2, wlo2); return; }
  b -= NW;
  if (b < NC) {
    newid[b * 1024 + tid] = -1;
    return;
  }
  if (tid < 64) {
    float a0 = 0.f, a1 = 0.f;
#pragma unroll
    for (int j = tid; j < 256; j += 64) {
      float v0 = pw0[j]; a0 += v0 * v0;
      float v1 = pw1[j]; a1 += v1 * v1;
    }
#pragma unroll
    for (int off = 32; off >= 1; off >>= 1) {
      a0 += __shfl_xor(a0, off);
      a1 += __shfl_xor(a1, off);
    }
    if (tid == 0) {
      norms[0] = 1.f / (sqrtf(a0) + 1e-16f);
      norms[1] = 1.f / (sqrtf(a1) + 1e-16f);
    }
  }
}

// -------- FUSED lin0+GAT0 GEMM, BM=32 x BN=256, 40 KB LDS (4 blocks/CU) -----
__global__ __launch_bounds__(256, 4) void gemm_fused(
    const unsigned short* __restrict__ Xhi, const unsigned short* __restrict__ Xlo,
    const unsigned short* __restrict__ B0hi, const unsigned short* __restrict__ B0lo,
    const float* __restrict__ bias0,
    const unsigned short* __restrict__ B1hi, const unsigned short* __restrict__ B1lo,
    float* __restrict__ Out,
    const float* __restrict__ attsrc, const float* __restrict__ attdst,
    float* __restrict__ a_s, float* __restrict__ a_d) {
  __shared__ __align__(16) unsigned short As[2][2][32][32];  // 8 KB
  __shared__ __align__(16) char Hsh[2][32 * 512];            // 32 KB
  const int tid = threadIdx.x;
  const int lane = tid & 63;
  const int w = tid >> 6;
  const int row0 = blockIdx.x * 32;
  const int l15 = lane & 15, q = lane >> 4;
  const int srow16 = lane >> 2;
  const int skc = (lane & 3) * 8;

  // wave w stages: half = w>>1 (0=hi plane, 1=lo plane), rows (w&1)*16 .. +15
  auto stage = [&](int nb, int kt) {
    const int half = w >> 1;
    const int r0 = (w & 1) * 16;
    const size_t goff = (size_t)(row0 + r0 + srow16) * KP + kt * 32 + skc;
    gload_lds16((half ? Xlo : Xhi) + goff, &As[nb][half][r0][0]);
  };

  f32x4 acc[2][4];
#pragma unroll
  for (int mf = 0; mf < 2; mf++)
#pragma unroll
    for (int nf = 0; nf < 4; nf++) acc[mf][nf] = (f32x4)(0.f);

  stage(0, 0);
  __syncthreads();

  // ---- stage 1: x @ W0 (5 k-tiles) ----
#pragma unroll
  for (int kt = 0; kt < 5; ++kt) {
    const int nb = kt & 1;
    if (kt + 1 < 5) stage(nb ^ 1, kt + 1);
    bf16x8 bh[4], bl[4];
#pragma unroll
    for (int nf = 0; nf < 4; nf++) {
      const int ct = w * 4 + nf;
      const size_t bbase = ((size_t)((kt * 16 + ct) * 64 + lane)) << 3;
      bh[nf] = *reinterpret_cast<const bf16x8*>(B0hi + bbase);
      bl[nf] = *reinterpret_cast<const bf16x8*>(B0lo + bbase);
    }
#pragma unroll
    for (int mf = 0; mf < 2; mf++) {
      const int ar = mf * 16 + l15;
      bf16x8 ah = *reinterpret_cast<const bf16x8*>(&As[nb][0][ar][q * 8]);
      bf16x8 al = *reinterpret_cast<const bf16x8*>(&As[nb][1][ar][q * 8]);
#pragma unroll
      for (int nf = 0; nf < 4; nf++) {
        acc[mf][nf] = __builtin_amdgcn_mfma_f32_16x16x32_bf16(ah, bh[nf], acc[mf][nf], 0, 0, 0);
        acc[mf][nf] = __builtin_amdgcn_mfma_f32_16x16x32_bf16(ah, bl[nf], acc[mf][nf], 0, 0, 0);
        acc[mf][nf] = __builtin_amdgcn_mfma_f32_16x16x32_bf16(al, bh[nf], acc[mf][nf], 0, 0, 0);
      }
    }
    __syncthreads();
  }

  // ---- epilogue 1: bias + ReLU -> Hsh (bf16 hi/lo, swizzled) ----
#pragma unroll
  for (int mf = 0; mf < 2; mf++) {
#pragma unroll
    for (int r = 0; r < 4; r++) {
      const int row = mf * 16 + q * 4 + r;
#pragma unroll
      for (int nf = 0; nf < 4; nf++) {
        const int col = w * 64 + nf * 16 + l15;
        float v = acc[mf][nf][r] + bias0[col];
        v = fmaxf(v, 0.f);
        unsigned short h = f2bf(v);
        unsigned short l = f2bf(v - bf2f(h));
        unsigned int off = (unsigned int)(row * 512 + col * 2) ^ ((row & 7) << 4);
        *reinterpret_cast<unsigned short*>(&Hsh[0][off]) = h;
        *reinterpret_cast<unsigned short*>(&Hsh[1][off]) = l;
        acc[mf][nf][r] = 0.f;
      }
    }
  }
  __syncthreads();

  // ---- stage 2: h @ W1 (8 k-tiles from LDS) ----
#pragma unroll
  for (int kt = 0; kt < 8; ++kt) {
    bf16x8 bh[4], bl[4];
#pragma unroll
    for (int nf = 0; nf < 4; nf++) {
      const int ct = w * 4 + nf;
      const size_t bbase = ((size_t)((kt * 16 + ct) * 64 + lane)) << 3;
      bh[nf] = *reinterpret_cast<const bf16x8*>(B1hi + bbase);
      bl[nf] = *reinterpret_cast<const bf16x8*>(B1lo + bbase);
    }
#pragma unroll
    for (int mf = 0; mf < 2; mf++) {
      const int ar = mf * 16 + l15;
      unsigned int off = (unsigned int)(ar * 512 + kt * 64 + q * 16) ^ ((ar & 7) << 4);
      bf16x8 ah = *reinterpret_cast<const bf16x8*>(&Hsh[0][off]);
      bf16x8 al = *reinterpret_cast<const bf16x8*>(&Hsh[1][off]);
#pragma unroll
      for (int nf = 0; nf < 4; nf++) {
        acc[mf][nf] = __builtin_amdgcn_mfma_f32_16x16x32_bf16(ah, bh[nf], acc[mf][nf], 0, 0, 0);
        acc[mf][nf] = __builtin_amdgcn_mfma_f32_16x16x32_bf16(ah, bl[nf], acc[mf][nf], 0, 0, 0);
        acc[mf][nf] = __builtin_amdgcn_mfma_f32_16x16x32_bf16(al, bh[nf], acc[mf][nf], 0, 0, 0);
      }
    }
  }

  // ---- epilogue 2: hW0 out + a_s/a_d ----
#pragma unroll
  for (int mf = 0; mf < 2; mf++) {
    const int rowb = row0 + mf * 16 + q * 4;
#pragma unroll
    for (int r = 0; r < 4; r++) {
#pragma unroll
      for (int nf = 0; nf < 4; nf++) {
        const int col = w * 64 + nf * 16 + l15;
        Out[(size_t)(rowb + r) * 256 + col] = acc[mf][nf][r];
      }
    }
  }
  const int head = w;
  float sv[4], dv[4];
#pragma unroll
  for (int nf = 0; nf < 4; nf++) {
    sv[nf] = attsrc[head * 64 + nf * 16 + l15];
    dv[nf] = attdst[head * 64 + nf * 16 + l15];
  }
#pragma unroll
  for (int mf = 0; mf < 2; mf++) {
#pragma unroll
    for (int r = 0; r < 4; r++) {
      float ps = 0.f, pd = 0.f;
#pragma unroll
      for (int nf = 0; nf < 4; nf++) {
        ps += acc[mf][nf][r] * sv[nf];
        pd += acc[mf][nf][r] * dv[nf];
      }
#pragma unroll
      for (int off = 8; off >= 1; off >>= 1) {
        ps += __shfl_xor(ps, off);
        pd += __shfl_xor(pd, off);
      }
      if (l15 == 0) {
        const int row = row0 + mf * 16 + q * 4 + r;
        a_s[(size_t)row * 4 + head] = ps;
        a_d[(size_t)row * 4 + head] = pd;
      }
    }
  }
}

// ------ split-bf16 GEMM (GAT1) + fused attpool_reduce(pool0) tail blocks ----
template <int KT, bool INDIR>
__global__ __launch_bounds__(256, 2) void gemm_mfma(
    const unsigned short* __restrict__ Xhi, const unsigned short* __restrict__ Xlo,
    int ldx,
    const unsigned short* __restrict__ Bhi, const unsigned short* __restrict__ Blo,
    float* __restrict__ Out,
    const float* __restrict__ attsrc, const float* __restrict__ attdst,
    float* __restrict__ a_s, float* __restrict__ a_d,
    const int* __restrict__ rowmap, const float* __restrict__ tscale, int swzl,
    int ngemm, const float* __restrict__ partials, float* __restrict__ outp,
    int nch) {
  __shared__ __align__(16) unsigned short As[2][2][128][32];  // 32 KB
  const int tid = threadIdx.x;
  if ((int)blockIdx.x >= ngemm) {
    int g = blockIdx.x - ngemm, c = tid;
    float a = 0.f;
    for (int s = 0; s < nch; s++) a += partials[((size_t)g * nch + s) * 256 + c];
    outp[g * 256 + c] = a;
    return;
  }
  const int lane = tid & 63;
  const int w = tid >> 6;
  const int rb = (swzl >= 0) ? swz_block(blockIdx.x, swzl) : blockIdx.x;
  const int row0 = rb * 128;
  const int l15 = lane & 15, q = lane >> 4;
  const int sl4 = lane >> 2;
  const int skc = (lane & 3) * 8;

  size_t gr[2];
#pragma unroll
  for (int i = 0; i < 2; i++) {
    int lr = row0 + (w + 4 * i) * 16 + sl4;
    gr[i] = INDIR ? (size_t)rowmap[lr] : (size_t)lr;
  }

  auto stage = [&](int nb, int kt) {
#pragma unroll
    for (int i = 0; i < 2; i++) {
      const int rbase = (w + 4 * i) * 16;
      const size_t goff = gr[i] * ldx + kt * 32 + skc;
      gload_lds16(Xhi + goff, &As[nb][0][rbase][0]);
      gload_lds16(Xlo + goff, &As[nb][1][rbase][0]);
    }
  };

  f32x4 acc[8][4];
#pragma unroll
  for (int mf = 0; mf < 8; mf++)
#pragma unroll
    for (int nf = 0; nf < 4; nf++) acc[mf][nf] = (f32x4)(0.f);

  stage(0, 0);
  __syncthreads();

#pragma unroll
  for (int kt = 0; kt < KT; ++kt) {
    const int nb = kt & 1;
    if (kt + 1 < KT) stage(nb ^ 1, kt + 1);
    bf16x8 bh[4], bl[4];
#pragma unroll
    for (int nf = 0; nf < 4; nf++) {
      const int ct = w * 4 + nf;
      const size_t bbase = ((size_t)((kt * 16 + ct) * 64 + lane)) << 3;
      bh[nf] = *reinterpret_cast<const bf16x8*>(Bhi + bbase);
      bl[nf] = *reinterpret_cast<const bf16x8*>(Blo + bbase);
    }
#pragma unroll
    for (int mf = 0; mf < 8; mf++) {
      const int ar = mf * 16 + l15;
      bf16x8 ah = *reinterpret_cast<const bf16x8*>(&As[nb][0][ar][q * 8]);
      bf16x8 al = *reinterpret_cast<const bf16x8*>(&As[nb][1][ar][q * 8]);
#pragma unroll
      for (int nf = 0; nf < 4; nf++) {
        acc[mf][nf] = __builtin_amdgcn_mfma_f32_16x16x32_bf16(ah, bh[nf], acc[mf][nf], 0, 0, 0);
        acc[mf][nf] = __builtin_amdgcn_mfma_f32_16x16x32_bf16(ah, bl[nf], acc[mf][nf], 0, 0, 0);
        acc[mf][nf] = __builtin_amdgcn_mfma_f32_16x16x32_bf16(al, bh[nf], acc[mf][nf], 0, 0, 0);
      }
    }
    __syncthreads();
  }

#pragma unroll
  for (int mf = 0; mf < 8; mf++) {
    const int rowb = row0 + mf * 16 + q * 4;
#pragma unroll
    for (int r = 0; r < 4; r++) {
      const float ts = INDIR ? tscale[rowb + r] : 1.f;
#pragma unroll
      for (int nf = 0; nf < 4; nf++) {
        float v = acc[mf][nf][r];
        if constexpr (INDIR) v *= ts;
        const int col = w * 64 + nf * 16 + l15;
        Out[(size_t)(rowb + r) * 256 + col] = v;
      }
    }
  }
  const int head = w;
  float sv[4], dv[4];
#pragma unroll
  for (int nf = 0; nf < 4; nf++) {
    sv[nf] = attsrc[head * 64 + nf * 16 + l15];
    dv[nf] = attdst[head * 64 + nf * 16 + l15];
  }
#pragma unroll
  for (int mf = 0; mf < 8; mf++) {
#pragma unroll
    for (int r = 0; r < 4; r++) {
      float ps = 0.f, pd = 0.f;
#pragma unroll
      for (int nf = 0; nf < 4; nf++) {
        ps += acc[mf][nf][r] * sv[nf];
        pd += acc[mf][nf][r] * dv[nf];
      }
#pragma unroll
      for (int off = 8; off >= 1; off >>= 1) {
        ps += __shfl_xor(ps, off);
        pd += __shfl_xor(pd, off);
      }
      if (l15 == 0) {
        const int row = row0 + mf * 16 + q * 4 + r;
        float ts = INDIR ? tscale[row] : 1.f;
        a_s[(size_t)row * 4 + head] = ps * ts;
        a_d[(size_t)row * 4 + head] = pd * ts;
      }
    }
  }
}

// --------- per-dest-node GAT: 2 nodes/wave; 16-lane group = node x 2 heads --
// LDS triple-table broadcast: softmax results written once to per-wave LDS,
// aggregation reads one float4/slot (bank-broadcast) instead of 3 ds_bpermute.
__global__ __launch_bounds__(256) void gat_node8(
    const int* __restrict__ cursor, const int* __restrict__ csr,
    const float* __restrict__ a_s, const float* __restrict__ a_d,
    const float* __restrict__ hW, const float* __restrict__ bias,
    const float* __restrict__ pool_w, const float* __restrict__ inv_norm,
    const float* __restrict__ gate_w,
    unsigned short* __restrict__ outHi, unsigned short* __restrict__ outLo,
    float* __restrict__ score, float* __restrict__ graw, int bpgl) {
  __shared__ __align__(16) float trip[4][4][64][4];  // 16 KB: [wave][grp][slot][{st,c0,c1,-}]
  const int lane = threadIdx.x & 63;
  const int wv = threadIdx.x >> 6;
  const int dbase = swz_block(blockIdx.x, bpgl) * 8 + wv * 2;
  const int g = lane >> 4, l16 = lane & 15;
  const int d = dbase + (g >> 1);
  const int h0 = (g & 1) * 2;

  const int deg = min(cursor[d], 63);
  const int dim = deg + 1;  // + self loop

  int dmaxw = dim;
  dmaxw = max(dmaxw, __shfl_xor(dmaxw, 32));
  const int nch = (dmaxw + 15) >> 4;

  const float2 ad2 = *reinterpret_cast<const float2*>(&a_d[(size_t)d * 4 + h0]);

  int sreg[4];
  float L0[4], L1[4];
#pragma unroll
  for (int c = 0; c < 4; c++) {
    if (c < nch) {
      const int j = c * 16 + l16;
      const bool has = j < dim;
      int s = (j < deg) ? csr[(size_t)d * 64 + j] : d;
      sreg[c] = s;
      float2 as2 = *reinterpret_cast<const float2*>(&a_s[(size_t)s * 4 + h0]);
      L0[c] = has ? leakyrelu(as2.x + ad2.x) : -1e30f;
      L1[c] = has ? leakyrelu(as2.y + ad2.y) : -1e30f;
    } else {
      sreg[c] = d;
      L0[c] = -1e30f; L1[c] = -1e30f;
    }
  }
  float m0 = fmaxf(fmaxf(L0[0], L0[1]), fmaxf(L0[2], L0[3]));
  float m1 = fmaxf(fmaxf(L1[0], L1[1]), fmaxf(L1[2], L1[3]));
#pragma unroll
  for (int off = 1; off <= 8; off <<= 1) {
    m0 = fmaxf(m0, __shfl_xor(m0, off));
    m1 = fmaxf(m1, __shfl_xor(m1, off));
  }
  float e0[4], e1[4];
  float dn0 = 0.f, dn1 = 0.f;
#pragma unroll
  for (int c = 0; c < 4; c++) {
    if (c < nch) {
      e0[c] = __expf(L0[c] - m0);
      e1[c] = __expf(L1[c] - m1);
      dn0 += e0[c]; dn1 += e1[c];
    } else {
      e0[c] = 0.f; e1[c] = 0.f;
    }
  }
#pragma unroll
  for (int off = 1; off <= 8; off <<= 1) {
    dn0 += __shfl_xor(dn0, off);
    dn1 += __shfl_xor(dn1, off);
  }

  // ---- publish (st, c0, c1) per slot to per-wave LDS (same-wave ordering,
  //      no barrier needed; reads below are same-address broadcasts) ----
#pragma unroll
  for (int c = 0; c < 4; c++) {
    float4 t;
    t.x = __int_as_float(sreg[c]);
    t.y = e0[c];
    t.z = e1[c];
    t.w = 0.f;
    *reinterpret_cast<float4*>(&trip[wv][g][c * 16 + l16][0]) = t;
  }

  float4 acc0 = {0.f, 0.f, 0.f, 0.f}, acc1 = {0.f, 0.f, 0.f, 0.f};
#pragma unroll
  for (int c = 0; c < 4; c++) {
    if (c < nch) {
      const int tmax = min(16, dmaxw - c * 16);
#pragma unroll 4
      for (int tt = 0; tt < tmax; tt++) {
        float4 t = *reinterpret_cast<const float4*>(&trip[wv][g][c * 16 + tt][0]);
        if (c * 16 + tt < dim) {
          const int st = __float_as_int(t.x);
          const float4* hp = reinterpret_cast<const float4*>(&hW[(size_t)st * 256]) + l16;
          acc0 = f4fma(hp[h0 * 16],       t.y, acc0);
          acc1 = f4fma(hp[(h0 + 1) * 16], t.z, acc1);
        }
      }
    }
  }

  const float iv0 = 1.f / (dn0 + 1e-16f), iv1 = 1.f / (dn1 + 1e-16f);
  float sd = 0.f, gd = 0.f;
#pragma unroll
  for (int h = 0; h < 2; h++) {
    const int coff = (h0 + h) * 64 + l16 * 4;
    float4 vb = h ? acc1 : acc0;
    float iv = h ? iv1 : iv0;
    float4 bb = *reinterpret_cast<const float4*>(&bias[coff]);
    float4 o;
    o.x = eluf(vb.x * iv + bb.x);
    o.y = eluf(vb.y * iv + bb.y);
    o.z = eluf(vb.z * iv + bb.z);
    o.w = eluf(vb.w * iv + bb.w);
    ushort4 oh, ol;
    oh.x = f2bf(o.x); ol.x = f2bf(o.x - bf2f(oh.x));
    oh.y = f2bf(o.y); ol.y = f2bf(o.y - bf2f(oh.y));
    oh.z = f2bf(o.z); ol.z = f2bf(o.z - bf2f(oh.z));
    oh.w = f2bf(o.w); ol.w = f2bf(o.w - bf2f(oh.w));
    *reinterpret_cast<ushort4*>(&outHi[(size_t)d * 256 + coff]) = oh;
    *reinterpret_cast<ushort4*>(&outLo[(size_t)d * 256 + coff]) = ol;
    float4 pw = *reinterpret_cast<const float4*>(&pool_w[coff]);
    float4 gw = *reinterpret_cast<const float4*>(&gate_w[coff]);
    sd += o.x * pw.x + o.y * pw.y + o.z * pw.z + o.w * pw.w;
    gd += o.x * gw.x + o.y * gw.y + o.z * gw.z + o.w * gw.w;
  }
#pragma unroll
  for (int off = 1; off <= 16; off <<= 1) {
    sd += __shfl_xor(sd, off);
    gd += __shfl_xor(gd, off);
  }
  if ((lane & 31) == 0) {
    score[d] = sd * inv_norm[0];
    graw[d] = gd;
  }
}

// ------- adaptive-range histogram top-k select + fused attpool softmax ------
__global__ __launch_bounds__(1024) void topk_hsel(
    const float* __restrict__ score, const float* __restrict__ graw,
    const float* __restrict__ gate_b, int npg, int k,
    int* __restrict__ perm, int* __restrict__ newid,
    float* __restrict__ gate, float* __restrict__ tsc) {
  __shared__ unsigned keys[2048];
  __shared__ int hist[1024];
  __shared__ int ssum[1024];
  __shared__ int segtot[16];
  __shared__ unsigned wmin[16], wmax[16];
  __shared__ int sstate[3];
  __shared__ int scnt;
  __shared__ int candi[512];
  __shared__ unsigned candk[512];
  __shared__ float fred[1024];
  const int g = blockIdx.x, tid = threadIdx.x;
  const int wv = tid >> 6, ln = tid & 63;
  const size_t base = (size_t)g * npg;

  unsigned mymin = 0xFFFFFFFFu, mymax = 0u;
  for (int i = tid; i < npg; i += 1024) {
    unsigned u = __float_as_uint(score[base + i]);
    u = (u & 0x80000000u) ? ~u : (u | 0x80000000u);
    keys[i] = u;
    mymin = min(mymin, u);
    mymax = max(mymax, u);
  }
#pragma unroll
  for (int off = 32; off >= 1; off >>= 1) {
    mymin = min(mymin, (unsigned)__shfl_xor((int)mymin, off));
    mymax = max(mymax, (unsigned)__shfl_xor((int)mymax, off));
  }
  if (ln == 0) { wmin[wv] = mymin; wmax[wv] = mymax; }
  __syncthreads();
  unsigned lo, hi;
  {
    unsigned a = 0xFFFFFFFFu, b = 0u;
#pragma unroll
    for (int i = 0; i < 16; i++) { a = min(a, wmin[i]); b = max(b, wmax[i]); }
    lo = a; hi = b;
  }
  int need = k;

  for (int iter = 0; iter < 4; ++iter) {
    unsigned long long range = (unsigned long long)(hi - lo) + 1ull;
    unsigned width = (unsigned)((range + 1023ull) >> 10);
    hist[tid] = 0;
    __syncthreads();
    for (int i = tid; i < npg; i += 1024) {
      unsigned u = keys[i];
      if (u >= lo && u <= hi) atomicAdd(&hist[(u - lo) / width], 1);
    }
    __syncthreads();
    int v = hist[tid];
    int s = v;
#pragma unroll
    for (int off = 1; off < 64; off <<= 1) {
      int t = __shfl_down(s, off);
      if (ln + off < 64) s += t;
    }
    if (ln == 0) segtot[wv] = s;
    __syncthreads();
    if (tid == 0) {
      int acc = 0;
      for (int i = 15; i >= 0; i--) { int t = segtot[i]; segtot[i] = acc; acc += t; }
    }
    __syncthreads();
    int S = s + segtot[wv];
    ssum[tid] = S;
    __syncthreads();
    int gt = (tid == 1023) ? 0 : ssum[tid + 1];
    if (S >= need && gt < need) {
      sstate[0] = tid;
      sstate[1] = gt;
      sstate[2] = hist[tid];
    }
    __syncthreads();
    const int bstar = sstate[0], cntAbove = sstate[1], m = sstate[2];
    unsigned nlo = lo + (unsigned)bstar * width;
    unsigned long long nhiu = (unsigned long long)lo + (unsigned long long)(bstar + 1) * width - 1ull;
    unsigned nhi = (nhiu > (unsigned long long)hi) ? hi : (unsigned)nhiu;
    need -= cntAbove;
    lo = nlo; hi = nhi;
    __syncthreads();
    if (width == 1 || m <= 256) break;
  }

  if (tid == 0) scnt = 0;
  __syncthreads();
  for (int i = tid; i < npg; i += 1024) {
    unsigned u = keys[i];
    if (u >= lo && u <= hi) {
      int pidx = atomicAdd(&scnt, 1);
      if (pidx < 512) { candi[pidx] = i; candk[pidx] = u; }
    }
  }
  __syncthreads();
  const int m_all = scnt;
  const float gb = gate_b[0];
  if (tid == 0) scnt = 0;
  __syncthreads();
  for (int i = tid; i < npg; i += 1024) {
    if (keys[i] > hi) {
      int pos = atomicAdd(&scnt, 1);
      int node = (int)(base + i);
      perm[g * k + pos] = node;
      if (newid) newid[node] = g * k + pos;
      float ts = ftanh(score[base + i]);
      tsc[g * k + pos] = ts;
      gate[g * k + pos] = ts * graw[node] + gb;
    }
  }
  __syncthreads();
  const int nAbove = scnt;
  if (m_all <= 512) {
    for (int c = tid; c < m_all; c += 1024) {
      unsigned u = candk[c];
      int i = candi[c];
      int rank = 0;
      for (int j = 0; j < m_all; j++) {
        unsigned vk = candk[j];
        rank += (vk > u) || (vk == u && candi[j] < i);
      }
      if (rank < need) {
        int pos = nAbove + rank;
        int node = (int)(base + i);
        perm[g * k + pos] = node;
        if (newid) newid[node] = g * k + pos;
        float ts = ftanh(score[base + i]);
        tsc[g * k + pos] = ts;
        gate[g * k + pos] = ts * graw[node] + gb;
      }
    }
  } else {
    for (int i = tid; i < npg; i += 1024) {
      unsigned u = keys[i];
      if (u >= lo && u <= hi) {
        int rank = 0;
        for (int j = 0; j < npg; j++) {
          unsigned vk = keys[j];
          if (vk >= lo && vk <= hi) rank += (vk > u) || (vk == u && j < i);
        }
        if (rank < need) {
          int pos = nAbove + rank;
          int node = (int)(base + i);
          perm[g * k + pos] = node;
          if (newid) newid[node] = g * k + pos;
          float ts = ftanh(score[base + i]);
          tsc[g * k + pos] = ts;
          gate[g * k + pos] = ts * graw[node] + gb;
        }
      }
    }
  }
  __syncthreads();

  // ---- fused attpool softmax: gate[j] <- exp(gate-m)/sum * tsc[j] ----
  float gv = (tid < k) ? gate[g * k + tid] : -1e30f;
  fred[tid] = gv;
  __syncthreads();
  for (int s = 512; s >= 1; s >>= 1) {
    if (tid < s) fred[tid] = fmaxf(fred[tid], fred[tid + s]);
    __syncthreads();
  }
  const float gm = fred[0];
  __syncthreads();
  float ge = (tid < k) ? __expf(gv - gm) : 0.f;
  fred[tid] = ge;
  __syncthreads();
  for (int s = 512; s >= 1; s >>= 1) {
    if (tid < s) fred[tid] += fred[tid + s];
    __syncthreads();
  }
  const float ginv = 1.f / fred[0];
  if (tid < k) gate[g * k + tid] = ge * ginv * tsc[g * k + tid];
}

// ---- pool tail (1024-thr): scatter1 slices FIRST (two-pass, 8 blocks/graph),
//      then attpool weighted gather-sum blocks (4 chunks/block) --------------
__global__ __launch_bounds__(1024) void pool_tail(
    const unsigned short* __restrict__ xhi, const unsigned short* __restrict__ xlo,
    const int* __restrict__ perm, const float* __restrict__ wfin,
    float* __restrict__ partials, int npg, int bpgl, int nsc,
    const int* __restrict__ src, const int* __restrict__ dst,
    const int* __restrict__ newid, int* __restrict__ cursor2,
    int* __restrict__ csr) {
  __shared__ int cnt[1024];
  __shared__ int basev[1024];
  const int tid = threadIdx.x;
  if ((int)blockIdx.x < nsc) {
    const int g = blockIdx.x / SLC, sl = blockIdx.x % SLC;
    const int e0 = g * EPG + sl * (EPG / SLC);
    const int ne = EPG / SLC;
    cnt[tid] = 0;
    __syncthreads();
    for (int i = tid; i < ne; i += 1024) {
      int e = e0 + i;
      int s = newid[src[e]], d = newid[dst[e]];
      if (s >= 0 && d >= 0) atomicAdd(&cnt[d - (g << 10)], 1);
    }
    __syncthreads();
    {
      int c = cnt[tid];
      basev[tid] = c ? atomicAdd(&cursor2[(g << 10) + tid], c) : 0;
    }
    __syncthreads();
    cnt[tid] = 0;
    __syncthreads();
    for (int i = tid; i < ne; i += 1024) {
      int e = e0 + i;
      int s = newid[src[e]], d = newid[dst[e]];
      if (s < 0 || d < 0) continue;
      int lb = d - (g << 10);
      int pos = basev[lb] + atomicAdd(&cnt[lb], 1);
      if (pos < 64) csr[(size_t)d * 64 + pos] = s;
    }
    return;
  }
  // attpool sum blocks
  int rel = blockIdx.x - nsc;
  int o = swz_block(rel, bpgl);
  int g = o >> bpgl, lb = o & ((1 << bpgl) - 1);
  int part = tid >> 8, c = tid & 255;
  int sub = lb * 4 + part;
  size_t r0 = (size_t)g * npg + sub * 32;
  float a = 0.f;
#pragma unroll 8
  for (int i = 0; i < 32; i++) {
    float wv = wfin[r0 + i];
    size_t node = (size_t)perm[r0 + i];
    float v = bf2f(xhi[node * 256 + c]) + bf2f(xlo[node * 256 + c]);
    a += wv * v;
  }
  partials[((size_t)g * (npg >> 5) + sub) * 256 + c] = a;
}

__global__ __launch_bounds__(256) void attpool_reduce(const float* __restrict__ partials,
                                                      float* __restrict__ out,
                                                      int nch, int acc_flag) {
  int g = blockIdx.x, c = threadIdx.x;
  float a = 0.f;
  for (int s = 0; s < nch; s++) a += partials[((size_t)g * nch + s) * 256 + c];
  if (acc_flag) out[g * 256 + c] += a;
  else out[g * 256 + c] = a;
}

}  // namespace

extern "C" void kernel_launch(void* const* d_in, const int* in_sizes, int n_in,
                              void* d_out, int out_size, void* d_ws, size_t ws_size,
                              hipStream_t stream) {
  (void)in_sizes; (void)n_in; (void)out_size; (void)ws_size;
  const float* x       = (const float*)d_in[0];
  const int*   ei      = (const int*)d_in[1];
  const float* lin0_w  = (const float*)d_in[2];
  const float* lin0_b  = (const float*)d_in[3];
  const float* gat0_W  = (const float*)d_in[4];
  const float* gat0_as = (const float*)d_in[5];
  const float* gat0_ad = (const float*)d_in[6];
  const float* gat0_b  = (const float*)d_in[7];
  const float* pool0_w = (const float*)d_in[8];
  const float* gat1_W  = (const float*)d_in[9];
  const float* gat1_as = (const float*)d_in[10];
  const float* gat1_ad = (const float*)d_in[11];
  const float* gat1_b  = (const float*)d_in[12];
  const float* pool1_w = (const float*)d_in[13];
  const float* gate_w  = (const float*)d_in[14];
  const float* gate_b  = (const float*)d_in[15];
  float* out = (float*)d_out;
  const int* srcp = ei;
  const int* dstp = ei + NE;

  char* wsb = (char*)d_ws;
  size_t cur = 0;
  auto alloc = [&](size_t bytes) {
    void* p = wsb + cur;
    cur = (cur + bytes + 255) & ~(size_t)255;
    return p;
  };
  char* regA = (char*)alloc((size_t)NN0 * 256 * 4);        // out0hi/lo
  char* regB = (char*)alloc((size_t)NN0 * 256 * 4);        // hW0 -> {hW1, out1hi/lo}
  char* regD = (char*)alloc((size_t)NN0 * KP * 2 * 2);     // xhi/xlo
  float* a_s     = (float*)alloc((size_t)NN0 * 4 * 4);
  float* a_d     = (float*)alloc((size_t)NN0 * 4 * 4);
  int*   cursor  = (int*)alloc((size_t)NN0 * 4);
  int*   cursor2 = (int*)alloc((size_t)32768 * 4);
  int*   csr     = (int*)alloc((size_t)NN0 * 64 * 4);
  float* score   = (float*)alloc((size_t)NN0 * 4);
  float* graw    = (float*)alloc((size_t)NN0 * 4);
  int*   newid   = (int*)alloc((size_t)NN0 * 4);
  int*   perm0   = (int*)alloc((size_t)32768 * 4);
  int*   perm1   = (int*)alloc((size_t)16384 * 4);
  float* tsc0    = (float*)alloc((size_t)32768 * 4);
  float* tsc1    = (float*)alloc((size_t)16384 * 4);
  float* gate0   = (float*)alloc((size_t)32768 * 4);
  float* gate1   = (float*)alloc((size_t)16384 * 4);
  float* partials= (float*)alloc((size_t)NB * 32 * 256 * 4);
  float* norms   = (float*)alloc(2 * 4);
  unsigned short* whi0 = (unsigned short*)alloc((size_t)5 * 8192 * 2);
  unsigned short* wlo0 = (unsigned short*)alloc((size_t)5 * 8192 * 2);
  unsigned short* whi1 = (unsigned short*)alloc((size_t)8 * 8192 * 2);
  unsigned short* wlo1 = (unsigned short*)alloc((size_t)8 * 8192 * 2);
  unsigned short* whi2 = (unsigned short*)alloc((size_t)8 * 8192 * 2);
  unsigned short* wlo2 = (unsigned short*)alloc((size_t)8 * 8192 * 2);

  unsigned short* xhi = (unsigned short*)regD;
  unsigned short* xlo = xhi + (size_t)NN0 * KP;
  float* hW0  = (float*)regB;
  unsigned short* out0hi = (unsigned short*)regA;
  unsigned short* out0lo = out0hi + (size_t)NN0 * 256;
  float* hW1  = (float*)regB;                              // overwrites hW0
  unsigned short* out1hi = (unsigned short*)(regB + (size_t)32768 * 256 * 4);
  unsigned short* out1lo = out1hi + (size_t)32768 * 256;

  // ---- zero cursors for the two-pass scatters (async, capture-safe) ----
  hipMemsetAsync(cursor, 0, (size_t)NN0 * 4, stream);
  hipMemsetAsync(cursor2, 0, (size_t)32768 * 4, stream);

  // ---- merged prep (scatter0 slices first, then packs) ----
  {
    int grid = NB * SLC + NN0 * KP / 8192 + 40 + 64 + 64 + 64 + 1;
    prep<<<grid, 1024, 0, stream>>>(x, lin0_w, gat0_W, gat1_W, pool0_w, pool1_w,
                                    srcp, dstp,
                                    xhi, xlo, whi0, wlo0, whi1, wlo1, whi2, wlo2,
                                    norms, newid, cursor, csr);
  }

  // ---- fused lin0+GAT0 GEMM -> hW0 + a_s/a_d (BM=32, 4 blocks/CU) ----
  gemm_fused<<<NN0 / 32, 256, 0, stream>>>(
      xhi, xlo, whi0, wlo0, lin0_b, whi1, wlo1, hW0,
      gat0_as, gat0_ad, a_s, a_d);

  gat_node8<<<NN0 / 8, 256, 0, stream>>>(cursor, csr, a_s, a_d, hW0,
                                         gat0_b, pool0_w, norms, gate_w,
                                         out0hi, out0lo, score, graw, 8);

  // ---- pool0: top-1024 of 2048 per graph (weights finalized in-kernel) ----
  topk_hsel<<<NB, 1024, 0, stream>>>(score, graw, gate_b, 2048, 1024,
                                     perm0, newid, gate0, tsc0);
  pool_tail<<<NB * SLC + NB * 8, 1024, 0, stream>>>(
      out0hi, out0lo, perm0, gate0, partials, 1024, 3, NB * SLC,
      srcp, dstp, newid, cursor2, csr);

  // ---- GAT1 GEMM (+ fused attpool_reduce(pool0) tail blocks) ----
  gemm_mfma<8, true><<<32768 / 128 + NB, 256, 0, stream>>>(
      out0hi, out0lo, 256, whi2, wlo2, hW1,
      gat1_as, gat1_ad, a_s, a_d, perm0, tsc0, 3,
      32768 / 128, partials, out, 32);

  gat_node8<<<32768 / 8, 256, 0, stream>>>(cursor2, csr, a_s, a_d, hW1,
                                           gat1_b, pool1_w, norms + 1, gate_w,
                                           out1hi, out1lo, score, graw, 7);

  // ---- pool1: top-512 of 1024 per graph ----
  topk_hsel<<<NB, 1024, 0, stream>>>(score, graw, gate_b, 1024, 512,
                                     perm1, nullptr, gate1, tsc1);
  pool_tail<<<NB * 4, 1024, 0, stream>>>(
      out1hi, out1lo, perm1, gate1, partials, 512, 2, 0,
      nullptr, nullptr, nullptr, nullptr, nullptr);
  attpool_reduce<<<NB, 256, 0, stream>>>(partials, out, 16, 1);
}